// Round 21
// baseline (2099.885 us; speedup 1.0000x reference)
//
#include <hip/hip_runtime.h>

typedef unsigned short u16;
typedef unsigned int   u32;
typedef unsigned long long u64;
typedef __attribute__((ext_vector_type(8)))  short  short8v;   // 8 x bf16 (as i16)
typedef __attribute__((ext_vector_type(4)))  float  f32x4;
typedef __attribute__((ext_vector_type(4)))  unsigned short ushort4v;
typedef __attribute__((ext_vector_type(4)))  u32 u32x4;

#define B_   32
#define T_   512
#define D_   1024
#define N4_  4096
#define NWG  256         // scan WGs: 128 unit-groups (8 units) x 2 batch halves (16 rows)

// ---- workspace layout (bytes) ----
#define OFF_XN   0ull                 // xn bf16   [32*512*1024]      33554432
#define OFF_HL   33554432ull          // h_last fp32 [32][1024]         131072
#define OFF_KT   167772160ull         // kernel^T bf16 [4096][1024]    8388608
#define OFF_RT   176160768ull         // recurrent^T bf16 [4096][1024] 8388608
#define OFF_HB   184549376ull         // h double buffer bf16 2*[32][1024] = 131072
#define OFF_FLG  184680448ull         // flags: 512 x 64B-strided u32 (2 gate-wave flags per WG)

__device__ inline u16 f2bf(float f) {
  union { float f; u32 u; } x; x.f = f;
  u32 r = x.u + 0x7FFFu + ((x.u >> 16) & 1u);   // RNE
  return (u16)(r >> 16);
}
__device__ inline float bf2f(u16 h) {
  union { u32 u; float f; } x; x.u = ((u32)h) << 16; return x.f;
}
__device__ inline float sigm(float x) { return 1.f / (1.f + __expf(-x)); }
__device__ inline float tanh_fast(float x) {
  float e = __expf(2.f * x);
  return 1.f - 2.f / (e + 1.f);
}

// ---------------- init: zero h buffers + flags ----------------
__global__ __launch_bounds__(256) void init_kernel(u32* hbuf, u32* flags) {
  int i = blockIdx.x * 256 + threadIdx.x;
  if (i < 32768) hbuf[i] = 0u;       // both parities: 2*32*1024 bf16 = 32768 dwords
  if (i < 512)   flags[i * 16] = 0u;
}

// ---------------- LN1: x fp32 -> xn bf16 ----------------
__global__ __launch_bounds__(256) void ln1_kernel(const float* __restrict__ x,
    const float* __restrict__ gam, const float* __restrict__ bet, u16* __restrict__ xn) {
  int row = blockIdx.x; int tid = threadIdx.x;
  const float* xr = x + (size_t)row * D_;
  float4 v = *(const float4*)(xr + tid * 4);
  float s  = v.x + v.y + v.z + v.w;
  float ss = v.x*v.x + v.y*v.y + v.z*v.z + v.w*v.w;
  #pragma unroll
  for (int o = 32; o > 0; o >>= 1) { s += __shfl_down(s, o); ss += __shfl_down(ss, o); }
  __shared__ float red[8];
  int w = tid >> 6, l = tid & 63;
  if (l == 0) { red[w] = s; red[4 + w] = ss; }
  __syncthreads();
  s  = red[0] + red[1] + red[2] + red[3];
  ss = red[4] + red[5] + red[6] + red[7];
  float mean = s * (1.f / D_);
  float var  = ss * (1.f / D_) - mean * mean;
  float rstd = rsqrtf(var + 1e-3f);
  float4 g = *(const float4*)(gam + tid * 4);
  float4 b = *(const float4*)(bet + tid * 4);
  ushort4v o4;
  o4.x = f2bf((v.x - mean) * rstd * g.x + b.x);
  o4.y = f2bf((v.y - mean) * rstd * g.y + b.y);
  o4.z = f2bf((v.z - mean) * rstd * g.z + b.z);
  o4.w = f2bf((v.w - mean) * rstd * g.w + b.w);
  *(ushort4v*)(xn + (size_t)row * D_ + tid * 4) = o4;
}

// ---------------- transpose [1024][4096] fp32 -> [4096][1024] bf16 ----------------
__global__ __launch_bounds__(256) void transpose_bf16(const float* __restrict__ W, u16* __restrict__ WT) {
  __shared__ float tile[32][33];
  int c0 = blockIdx.x * 32, r0 = blockIdx.y * 32;
  int tx = threadIdx.x, ty = threadIdx.y;
  #pragma unroll
  for (int i = ty; i < 32; i += 8)
    tile[i][tx] = W[(size_t)(r0 + i) * N4_ + c0 + tx];
  __syncthreads();
  #pragma unroll
  for (int i = ty; i < 32; i += 8)
    WT[(size_t)(c0 + i) * D_ + r0 + tx] = f2bf(tile[tx][i]);
}

// ---------------- persistent LSTM scan (R21: wave7 poller + xn prefetch + lgkm barriers) ----
// 256 WGs x 512 thr = 128 unit-groups (8 units, 32 gate-cols) x 2 batch halves
// (16 rows). Base = R20 champion (fused Zx, coalesced staging, 2-wave gates with
// per-gate-wave flags). Three chain cuts:
//  (a) poller moved to WAVE 7 (no gate duty): poll spins DURING local gates, so
//      detection is latched by the time gate waves reach the s_barrier.
//  (b) xn A-fragments for step t+1 issued as pinned asm prefetches at the z-write
//      point of step t — their L3 latency hides under barrier+gates+poll.
//  (c) both intra-step barriers use s_waitcnt lgkmcnt(0) + raw s_barrier
//      (__syncthreads would drain vmcnt(0) and kill the prefetch; only LDS
//      visibility is required there — staging has its own explicit vmcnt drain).
__global__ __launch_bounds__(512) __attribute__((amdgpu_waves_per_eu(2, 2)))
void lstm_scan(const u16* __restrict__ xn, const u16* __restrict__ KT,
    const u16* __restrict__ RT, const float* __restrict__ bias,
    u16* hbuf, float* h_last, u32* flags) {
  __shared__ u16   h_lds[16 * D_];           // 32 KB, XOR-swizzled rows (16 batch rows)
  __shared__ float z_lds[8 * 16 * 36];       // 18 KB: [ks][row16][32 cols + 4 pad]
  int tid = threadIdx.x;
  int wg = blockIdx.x;
  int ug = wg >> 1, bh = wg & 1;             // unit-group, batch half
  int w = tid >> 6, l = tid & 63;
  int ks = w;                                // K-split: ks*128..+128
  int fr = l & 15, hi = l >> 4;              // fragment row 0..15, k-quarter 0..3

  // B fragments: col c = ch*16+fr -> unit ug*8+(c>>2), gate c&3.
  short8v bR[4][2], bK[4][2];
  #pragma unroll
  for (int ch = 0; ch < 2; ++ch) {
    int c = ch * 16 + fr;
    size_t rowoff = (size_t)((c & 3) * 1024 + ug * 8 + (c >> 2)) * D_
                  + ks * 128 + hi * 8;
    const u16* Rp = RT + rowoff;
    const u16* Kp = KT + rowoff;
    #pragma unroll
    for (int kt = 0; kt < 4; ++kt) {
      bR[kt][ch] = *(const short8v*)(Rp + kt * 32);
      bK[kt][ch] = *(const short8v*)(Kp + kt * 32);
    }
  }
  #pragma unroll
  for (int kt = 0; kt < 4; ++kt) {
    asm volatile("" : "+v"(bR[kt][0]));
    asm volatile("" : "+v"(bR[kt][1]));
    asm volatile("" : "+v"(bK[kt][0]));
    asm volatile("" : "+v"(bK[kt][1]));
  }

  // xn A-operand pointer: row b = bh*16+fr, time t
  const u16* xnp = xn + (size_t)(bh * 16 + fr) * 512 * D_ + ks * 128 + hi * 8;
  // h A-fragment addressing (staged LDS, swizzled)
  int abase = fr * 2048 + ks * 256 + hi * 16;
  int asw = (fr & 7) << 4;
  // gate cell (tid < 128): local batch row grow (0..15), unit gu (0..7)
  int grow = tid >> 3, gu = tid & 7;
  int hoff = (bh * 16 + grow) * D_ + ug * 8 + gu;
  float c = 0.f;
  float bi0 = 0.f, bf0 = 0.f, bg0 = 0.f, bo0 = 0.f;
  if (tid < 128) {
    int u = ug * 8 + gu;
    bi0 = bias[u]; bf0 = bias[1024 + u]; bg0 = bias[2048 + u]; bo0 = bias[3072 + u];
  }
  // wave7 poll: 128 same-bh WGs x 2 gate-flags = 4 per lane
  const u32* fpA0 = flags + (size_t)((2 * l + bh) * 2 + 0) * 16;
  const u32* fpA1 = flags + (size_t)((2 * l + bh) * 2 + 1) * 16;
  const u32* fpB0 = flags + (size_t)((2 * (64 + l) + bh) * 2 + 0) * 16;
  const u32* fpB1 = flags + (size_t)((2 * (64 + l) + bh) * 2 + 1) * 16;

  // prologue: xn fragments for t=0
  short8v ax[4];
  #pragma unroll
  for (int kt = 0; kt < 4; ++kt) ax[kt] = *(const short8v*)(xnp + kt * 32);

  #pragma unroll 1
  for (int t = 0; t < T_; ++t) {
    // (1) fused Zx part: 8 MFMAs on the PREFETCHED xn fragments
    asm volatile("s_waitcnt vmcnt(0)" ::: "memory");   // ax prefetch landed long ago
    f32x4 acc0, acc1;
    #pragma unroll
    for (int i = 0; i < 4; ++i) { acc0[i] = 0.f; acc1[i] = 0.f; }
    #pragma unroll
    for (int kt = 0; kt < 4; ++kt) {
      acc0 = __builtin_amdgcn_mfma_f32_16x16x32_bf16(ax[kt], bK[kt][0], acc0, 0, 0, 0);
      acc1 = __builtin_amdgcn_mfma_f32_16x16x32_bf16(ax[kt], bK[kt][1], acc1, 0, 0, 0);
    }
    __builtin_amdgcn_sched_barrier(0);

    // (2) wave7 (non-gate) polls same-bh flags; s_barrier releases everyone
    if (w == 7) {
      u32 t32 = (u32)t;
      while (true) {
        u32 a0 = __hip_atomic_load(fpA0, __ATOMIC_RELAXED, __HIP_MEMORY_SCOPE_AGENT);
        u32 a1 = __hip_atomic_load(fpA1, __ATOMIC_RELAXED, __HIP_MEMORY_SCOPE_AGENT);
        u32 b0 = __hip_atomic_load(fpB0, __ATOMIC_RELAXED, __HIP_MEMORY_SCOPE_AGENT);
        u32 b1 = __hip_atomic_load(fpB1, __ATOMIC_RELAXED, __HIP_MEMORY_SCOPE_AGENT);
        if (__all((int)(a0 >= t32 && a1 >= t32 && b0 >= t32 && b1 >= t32))) break;
      }
    }
    __builtin_amdgcn_s_barrier();
    __builtin_amdgcn_sched_barrier(0);

    // (3) bulk-load h for our 16 batch rows: 4 x 16B per thread (32KB, coalesced)
    const char* hbp = (const char*)hbuf + (size_t)(t & 1) * 65536 + (size_t)bh * 32768;
    u32x4 hv[4];
    #pragma unroll
    for (int j = 0; j < 4; ++j) {
      const char* p = hbp + j * 8192 + tid * 16;
      asm volatile("global_load_dwordx4 %0, %1, off sc0 sc1"
                   : "=&v"(hv[j]) : "v"(p) : "memory");
    }
    asm volatile("s_waitcnt vmcnt(0)" ::: "memory");
    __builtin_amdgcn_sched_barrier(0);
    #pragma unroll
    for (int j = 0; j < 4; ++j) {
      int byte = j * 8192 + tid * 16;
      int row = byte >> 11;
      *(u32x4*)((char*)h_lds + (byte ^ ((row & 7) << 4))) = hv[j];
    }
    // staging barrier: LDS-only drain (keep vmem prefetches in flight)
    asm volatile("s_waitcnt lgkmcnt(0)" ::: "memory");
    __builtin_amdgcn_s_barrier();
    __builtin_amdgcn_sched_barrier(0);

    // (4) h-part: 4 K-steps x (1 ds_read_b128 + 2 mfma 16x16x32) onto Zx accs
    #pragma unroll
    for (int kt = 0; kt < 4; ++kt) {
      short8v a = *(const short8v*)((const char*)h_lds + ((abase + kt * 64) ^ asw));
      acc0 = __builtin_amdgcn_mfma_f32_16x16x32_bf16(a, bR[kt][0], acc0, 0, 0, 0);
      acc1 = __builtin_amdgcn_mfma_f32_16x16x32_bf16(a, bR[kt][1], acc1, 0, 0, 0);
    }
    // write K-partials: 16x16 D layout row=hi*4+j, col=fr
    #pragma unroll
    for (int j = 0; j < 4; ++j) {
      int rowD = hi * 4 + j;
      z_lds[(ks * 16 + rowD) * 36 + fr]      = acc0[j];
      z_lds[(ks * 16 + rowD) * 36 + 16 + fr] = acc1[j];
    }
    // prefetch xn fragments for t+1 (pinned issue; fly across barrier+gates+poll)
    {
      const u16* xq = xnp + D_;
      #pragma unroll
      for (int kt = 0; kt < 4; ++kt) {
        const u16* p = xq + kt * 32;
        asm volatile("global_load_dwordx4 %0, %1, off"
                     : "=&v"(ax[kt]) : "v"(p) : "memory");
      }
    }
    // z barrier: LDS-only drain (prefetch stays in flight)
    asm volatile("s_waitcnt lgkmcnt(0)" ::: "memory");
    __builtin_amdgcn_s_barrier();
    __builtin_amdgcn_sched_barrier(0);

    // (5) gates: waves 0-1 (128 thr, one cell each); waves 2-7 go straight to t+1
    if (tid < 128) {
      float z0 = bi0, z1 = bf0, z2 = bg0, z3 = bo0;
      #pragma unroll
      for (int kss = 0; kss < 8; ++kss) {
        f32x4 zr = *(const f32x4*)&z_lds[(kss * 16 + grow) * 36 + gu * 4];
        z0 += zr[0]; z1 += zr[1]; z2 += zr[2]; z3 += zr[3];
      }
      float cn = sigm(z1) * c + sigm(z0) * tanh_fast(z2);
      float hn = sigm(z3) * tanh_fast(cn);
      c = cn;

      // publish h (pair adjacent units -> u32 agent-scope store)
      u32 hw = (u32)f2bf(hn);
      u32 nb = __shfl_down(hw, 1);
      if (!(gu & 1)) {
        u32* dst = (u32*)(hbuf + (size_t)((t + 1) & 1) * (B_ * D_) + hoff);
        __hip_atomic_store(dst, hw | (nb << 16), __ATOMIC_RELAXED, __HIP_MEMORY_SCOPE_AGENT);
      }
      if (t == T_ - 1) h_last[hoff] = hn;
      // wave-local drain, then set THIS gate wave's flag
      asm volatile("s_waitcnt vmcnt(0)" ::: "memory");
      if (l == 0)
        __hip_atomic_store(flags + (size_t)(wg * 2 + w) * 16, (u32)(t + 1),
                           __ATOMIC_RELAXED, __HIP_MEMORY_SCOPE_AGENT);
    }
    xnp += D_;
  }
}

// ---------------- LN2: out = LN(xn + h_last) fp32 ----------------
__global__ __launch_bounds__(256) void ln2_kernel(const u16* __restrict__ xn,
    const float* __restrict__ h_last, const float* __restrict__ gam,
    const float* __restrict__ bet, float* __restrict__ out) {
  int row = blockIdx.x; int tid = threadIdx.x;
  int bi = row >> 9;
  ushort4v xv = *(const ushort4v*)(xn + (size_t)row * D_ + tid * 4);
  float4 hv = *(const float4*)(h_last + (size_t)bi * D_ + tid * 4);
  float s0 = bf2f(xv.x) + hv.x;
  float s1 = bf2f(xv.y) + hv.y;
  float s2 = bf2f(xv.z) + hv.z;
  float s3 = bf2f(xv.w) + hv.w;
  float s = s0 + s1 + s2 + s3;
  float ss = s0*s0 + s1*s1 + s2*s2 + s3*s3;
  #pragma unroll
  for (int o = 32; o > 0; o >>= 1) { s += __shfl_down(s, o); ss += __shfl_down(ss, o); }
  __shared__ float red[8];
  int w = tid >> 6, l = tid & 63;
  if (l == 0) { red[w] = s; red[4 + w] = ss; }
  __syncthreads();
  s  = red[0] + red[1] + red[2] + red[3];
  ss = red[4] + red[5] + red[6] + red[7];
  float mean = s * (1.f / D_);
  float var  = ss * (1.f / D_) - mean * mean;
  float rstd = rsqrtf(var + 1e-3f);
  float4 g = *(const float4*)(gam + tid * 4);
  float4 b = *(const float4*)(bet + tid * 4);
  float4 o4;
  o4.x = (s0 - mean) * rstd * g.x + b.x;
  o4.y = (s1 - mean) * rstd * g.y + b.y;
  o4.z = (s2 - mean) * rstd * g.z + b.z;
  o4.w = (s3 - mean) * rstd * g.w + b.w;
  *(float4*)(out + (size_t)row * D_ + tid * 4) = o4;
}

extern "C" void kernel_launch(void* const* d_in, const int* in_sizes, int n_in,
                              void* d_out, int out_size, void* d_ws, size_t ws_size,
                              hipStream_t stream) {
  const float* x    = (const float*)d_in[0];
  const float* g1   = (const float*)d_in[1];
  const float* b1   = (const float*)d_in[2];
  const float* Wk   = (const float*)d_in[3];
  const float* Wr   = (const float*)d_in[4];
  const float* bias = (const float*)d_in[5];
  const float* g2   = (const float*)d_in[6];
  const float* b2   = (const float*)d_in[7];
  char* ws = (char*)d_ws;
  u16* xn    = (u16*)(ws + OFF_XN);
  u16* KT    = (u16*)(ws + OFF_KT);
  u16* RT    = (u16*)(ws + OFF_RT);
  u16* hbuf  = (u16*)(ws + OFF_HB);
  u32* flg   = (u32*)(ws + OFF_FLG);
  float* hl  = (float*)(ws + OFF_HL);
  float* out = (float*)d_out;

  init_kernel<<<128, 256, 0, stream>>>((u32*)hbuf, flg);
  ln1_kernel<<<B_ * T_, 256, 0, stream>>>(x, g1, b1, xn);
  transpose_bf16<<<dim3(128, 32), dim3(32, 8), 0, stream>>>(Wk, KT);
  transpose_bf16<<<dim3(128, 32), dim3(32, 8), 0, stream>>>(Wr, RT);
  lstm_scan<<<NWG, 512, 0, stream>>>(xn, KT, RT, bias, hbuf, hl, flg);
  ln2_kernel<<<B_ * T_, 256, 0, stream>>>(xn, hl, g2, b2, out);
}

// Round 22
// 1611.580 us; speedup vs baseline: 1.3030x; 1.3030x over previous
//
#include <hip/hip_runtime.h>

typedef unsigned short u16;
typedef unsigned int   u32;
typedef unsigned long long u64;
typedef __attribute__((ext_vector_type(8)))  short  short8v;   // 8 x bf16 (as i16)
typedef __attribute__((ext_vector_type(4)))  float  f32x4;
typedef __attribute__((ext_vector_type(4)))  unsigned short ushort4v;
typedef __attribute__((ext_vector_type(4)))  u32 u32x4;

#define B_   32
#define T_   512
#define D_   1024
#define N4_  4096
#define NWG  256         // scan WGs: 128 unit-groups (8 units) x 2 batch halves (16 rows)

// ---- workspace layout (bytes) ----
#define OFF_XN   0ull                 // xn bf16   [32*512*1024]      33554432
#define OFF_HL   33554432ull          // h_last fp32 [32][1024]         131072
#define OFF_KT   167772160ull         // kernel^T bf16 [4096][1024]    8388608
#define OFF_RT   176160768ull         // recurrent^T bf16 [4096][1024] 8388608
#define OFF_HB   184549376ull         // h double buffer bf16 2*[32][1024] = 131072
#define OFF_FLG  184680448ull         // flags: 512 x 64B-strided u32 (2 gate-wave flags per WG)

__device__ inline u16 f2bf(float f) {
  union { float f; u32 u; } x; x.f = f;
  u32 r = x.u + 0x7FFFu + ((x.u >> 16) & 1u);   // RNE
  return (u16)(r >> 16);
}
__device__ inline float bf2f(u16 h) {
  union { u32 u; float f; } x; x.u = ((u32)h) << 16; return x.f;
}
__device__ inline float sigm(float x) { return 1.f / (1.f + __expf(-x)); }
__device__ inline float tanh_fast(float x) {
  float e = __expf(2.f * x);
  return 1.f - 2.f / (e + 1.f);
}

// ---------------- init: zero h buffers + flags ----------------
__global__ __launch_bounds__(256) void init_kernel(u32* hbuf, u32* flags) {
  int i = blockIdx.x * 256 + threadIdx.x;
  if (i < 32768) hbuf[i] = 0u;       // both parities: 2*32*1024 bf16 = 32768 dwords
  if (i < 512)   flags[i * 16] = 0u;
}

// ---------------- LN1: x fp32 -> xn bf16 ----------------
__global__ __launch_bounds__(256) void ln1_kernel(const float* __restrict__ x,
    const float* __restrict__ gam, const float* __restrict__ bet, u16* __restrict__ xn) {
  int row = blockIdx.x; int tid = threadIdx.x;
  const float* xr = x + (size_t)row * D_;
  float4 v = *(const float4*)(xr + tid * 4);
  float s  = v.x + v.y + v.z + v.w;
  float ss = v.x*v.x + v.y*v.y + v.z*v.z + v.w*v.w;
  #pragma unroll
  for (int o = 32; o > 0; o >>= 1) { s += __shfl_down(s, o); ss += __shfl_down(ss, o); }
  __shared__ float red[8];
  int w = tid >> 6, l = tid & 63;
  if (l == 0) { red[w] = s; red[4 + w] = ss; }
  __syncthreads();
  s  = red[0] + red[1] + red[2] + red[3];
  ss = red[4] + red[5] + red[6] + red[7];
  float mean = s * (1.f / D_);
  float var  = ss * (1.f / D_) - mean * mean;
  float rstd = rsqrtf(var + 1e-3f);
  float4 g = *(const float4*)(gam + tid * 4);
  float4 b = *(const float4*)(bet + tid * 4);
  ushort4v o4;
  o4.x = f2bf((v.x - mean) * rstd * g.x + b.x);
  o4.y = f2bf((v.y - mean) * rstd * g.y + b.y);
  o4.z = f2bf((v.z - mean) * rstd * g.z + b.z);
  o4.w = f2bf((v.w - mean) * rstd * g.w + b.w);
  *(ushort4v*)(xn + (size_t)row * D_ + tid * 4) = o4;
}

// ---------------- transpose [1024][4096] fp32 -> [4096][1024] bf16 ----------------
__global__ __launch_bounds__(256) void transpose_bf16(const float* __restrict__ W, u16* __restrict__ WT) {
  __shared__ float tile[32][33];
  int c0 = blockIdx.x * 32, r0 = blockIdx.y * 32;
  int tx = threadIdx.x, ty = threadIdx.y;
  #pragma unroll
  for (int i = ty; i < 32; i += 8)
    tile[i][tx] = W[(size_t)(r0 + i) * N4_ + c0 + tx];
  __syncthreads();
  #pragma unroll
  for (int i = ty; i < 32; i += 8)
    WT[(size_t)(c0 + i) * D_ + r0 + tx] = f2bf(tile[tx][i]);
}

// ---------------- persistent LSTM scan (R22: R20 champion + wave7 poller ONLY) ----------------
// 256 WGs x 512 thr = 128 unit-groups (8 units, 32 gate-cols) x 2 batch halves
// (16 rows). Byte-identical to R20 except ONE change: the flag poll runs in
// WAVE 7 (which has no gate duty) instead of wave 0. Wave 7's Zx+poll-spin now
// runs CONCURRENTLY with waves 0-1's gates+flag-publish, so remote-flag
// detection is latched by the time gate waves reach the release s_barrier.
// (R21 bundled this with prefetch + lgkm-barrier changes and regressed; this
// round isolates the single variable.)
__global__ __launch_bounds__(512) __attribute__((amdgpu_waves_per_eu(2, 2)))
void lstm_scan(const u16* __restrict__ xn, const u16* __restrict__ KT,
    const u16* __restrict__ RT, const float* __restrict__ bias,
    u16* hbuf, float* h_last, u32* flags) {
  __shared__ u16   h_lds[16 * D_];           // 32 KB, XOR-swizzled rows (16 batch rows)
  __shared__ float z_lds[8 * 16 * 36];       // 18 KB: [ks][row16][32 cols + 4 pad]
  int tid = threadIdx.x;
  int wg = blockIdx.x;
  int ug = wg >> 1, bh = wg & 1;             // unit-group, batch half
  int w = tid >> 6, l = tid & 63;
  int ks = w;                                // K-split: ks*128..+128
  int fr = l & 15, hi = l >> 4;              // fragment row 0..15, k-quarter 0..3

  // B fragments: col c = ch*16+fr -> unit ug*8+(c>>2), gate c&3.
  short8v bR[4][2], bK[4][2];
  #pragma unroll
  for (int ch = 0; ch < 2; ++ch) {
    int c = ch * 16 + fr;
    size_t rowoff = (size_t)((c & 3) * 1024 + ug * 8 + (c >> 2)) * D_
                  + ks * 128 + hi * 8;
    const u16* Rp = RT + rowoff;
    const u16* Kp = KT + rowoff;
    #pragma unroll
    for (int kt = 0; kt < 4; ++kt) {
      bR[kt][ch] = *(const short8v*)(Rp + kt * 32);
      bK[kt][ch] = *(const short8v*)(Kp + kt * 32);
    }
  }
  #pragma unroll
  for (int kt = 0; kt < 4; ++kt) {
    asm volatile("" : "+v"(bR[kt][0]));
    asm volatile("" : "+v"(bR[kt][1]));
    asm volatile("" : "+v"(bK[kt][0]));
    asm volatile("" : "+v"(bK[kt][1]));
  }

  // xn A-operand pointer: row b = bh*16+fr, time t
  const u16* xnp = xn + (size_t)(bh * 16 + fr) * 512 * D_ + ks * 128 + hi * 8;
  // h A-fragment addressing (staged LDS, swizzled)
  int abase = fr * 2048 + ks * 256 + hi * 16;
  int asw = (fr & 7) << 4;
  // gate cell (tid < 128): local batch row grow (0..15), unit gu (0..7)
  int grow = tid >> 3, gu = tid & 7;
  int hoff = (bh * 16 + grow) * D_ + ug * 8 + gu;
  float c = 0.f;
  float bi0 = 0.f, bf0 = 0.f, bg0 = 0.f, bo0 = 0.f;
  if (tid < 128) {
    int u = ug * 8 + gu;
    bi0 = bias[u]; bf0 = bias[1024 + u]; bg0 = bias[2048 + u]; bo0 = bias[3072 + u];
  }
  // wave7 poll: 128 same-bh WGs x 2 gate-flags = 4 per lane
  // flag index for (wg', gw) = (wg'*2+gw); wg' = ug'*2+bh
  const u32* fpA0 = flags + (size_t)((2 * l + bh) * 2 + 0) * 16;
  const u32* fpA1 = flags + (size_t)((2 * l + bh) * 2 + 1) * 16;
  const u32* fpB0 = flags + (size_t)((2 * (64 + l) + bh) * 2 + 0) * 16;
  const u32* fpB1 = flags + (size_t)((2 * (64 + l) + bh) * 2 + 1) * 16;

  #pragma unroll 1
  for (int t = 0; t < T_; ++t) {
    // (1) fused Zx part: 4 direct xn loads (cached) + 8 MFMAs — no h dependency
    f32x4 acc0, acc1;
    #pragma unroll
    for (int i = 0; i < 4; ++i) { acc0[i] = 0.f; acc1[i] = 0.f; }
    {
      short8v ax[4];
      #pragma unroll
      for (int kt = 0; kt < 4; ++kt) ax[kt] = *(const short8v*)(xnp + kt * 32);
      #pragma unroll
      for (int kt = 0; kt < 4; ++kt) {
        acc0 = __builtin_amdgcn_mfma_f32_16x16x32_bf16(ax[kt], bK[kt][0], acc0, 0, 0, 0);
        acc1 = __builtin_amdgcn_mfma_f32_16x16x32_bf16(ax[kt], bK[kt][1], acc1, 0, 0, 0);
      }
    }
    __builtin_amdgcn_sched_barrier(0);

    // (2) wave7 (no gate duty) polls same-bh flags concurrently with waves 0-1's
    //     gates+flag from step t-1; s_barrier releases everyone
    if (w == 7) {
      u32 t32 = (u32)t;
      while (true) {
        u32 a0 = __hip_atomic_load(fpA0, __ATOMIC_RELAXED, __HIP_MEMORY_SCOPE_AGENT);
        u32 a1 = __hip_atomic_load(fpA1, __ATOMIC_RELAXED, __HIP_MEMORY_SCOPE_AGENT);
        u32 b0 = __hip_atomic_load(fpB0, __ATOMIC_RELAXED, __HIP_MEMORY_SCOPE_AGENT);
        u32 b1 = __hip_atomic_load(fpB1, __ATOMIC_RELAXED, __HIP_MEMORY_SCOPE_AGENT);
        if (__all((int)(a0 >= t32 && a1 >= t32 && b0 >= t32 && b1 >= t32))) break;
      }
    }
    __builtin_amdgcn_s_barrier();
    __builtin_amdgcn_sched_barrier(0);

    // (3) bulk-load h for our 16 batch rows: 4 x 16B per thread (32KB, coalesced)
    const char* hbp = (const char*)hbuf + (size_t)(t & 1) * 65536 + (size_t)bh * 32768;
    u32x4 hv[4];
    #pragma unroll
    for (int j = 0; j < 4; ++j) {
      const char* p = hbp + j * 8192 + tid * 16;
      asm volatile("global_load_dwordx4 %0, %1, off sc0 sc1"
                   : "=&v"(hv[j]) : "v"(p) : "memory");
    }
    asm volatile("s_waitcnt vmcnt(0)" ::: "memory");
    __builtin_amdgcn_sched_barrier(0);
    #pragma unroll
    for (int j = 0; j < 4; ++j) {
      int byte = j * 8192 + tid * 16;
      int row = byte >> 11;
      *(u32x4*)((char*)h_lds + (byte ^ ((row & 7) << 4))) = hv[j];
    }
    __syncthreads();

    // (4) h-part: 4 K-steps x (1 ds_read_b128 + 2 mfma 16x16x32) onto Zx accs
    #pragma unroll
    for (int kt = 0; kt < 4; ++kt) {
      short8v a = *(const short8v*)((const char*)h_lds + ((abase + kt * 64) ^ asw));
      acc0 = __builtin_amdgcn_mfma_f32_16x16x32_bf16(a, bR[kt][0], acc0, 0, 0, 0);
      acc1 = __builtin_amdgcn_mfma_f32_16x16x32_bf16(a, bR[kt][1], acc1, 0, 0, 0);
    }
    // write K-partials: 16x16 D layout row=hi*4+j, col=fr
    #pragma unroll
    for (int j = 0; j < 4; ++j) {
      int rowD = hi * 4 + j;
      z_lds[(ks * 16 + rowD) * 36 + fr]      = acc0[j];
      z_lds[(ks * 16 + rowD) * 36 + 16 + fr] = acc1[j];
    }
    __syncthreads();   // z visible to gate waves; ALSO proves all h(t) reads done

    // (5) gates: waves 0-1 (128 thr, one cell each); waves 2-7 go straight to t+1
    if (tid < 128) {
      float z0 = bi0, z1 = bf0, z2 = bg0, z3 = bo0;
      #pragma unroll
      for (int kss = 0; kss < 8; ++kss) {
        f32x4 zr = *(const f32x4*)&z_lds[(kss * 16 + grow) * 36 + gu * 4];
        z0 += zr[0]; z1 += zr[1]; z2 += zr[2]; z3 += zr[3];
      }
      float cn = sigm(z1) * c + sigm(z0) * tanh_fast(z2);
      float hn = sigm(z3) * tanh_fast(cn);
      c = cn;

      // publish h (pair adjacent units -> u32 agent-scope store)
      u32 hw = (u32)f2bf(hn);
      u32 nb = __shfl_down(hw, 1);
      if (!(gu & 1)) {
        u32* dst = (u32*)(hbuf + (size_t)((t + 1) & 1) * (B_ * D_) + hoff);
        __hip_atomic_store(dst, hw | (nb << 16), __ATOMIC_RELAXED, __HIP_MEMORY_SCOPE_AGENT);
      }
      if (t == T_ - 1) h_last[hoff] = hn;
      // wave-local drain, then set THIS gate wave's flag (no cross-wave barrier)
      asm volatile("s_waitcnt vmcnt(0)" ::: "memory");
      if (l == 0)
        __hip_atomic_store(flags + (size_t)(wg * 2 + w) * 16, (u32)(t + 1),
                           __ATOMIC_RELAXED, __HIP_MEMORY_SCOPE_AGENT);
    }
    xnp += D_;
  }
}

// ---------------- LN2: out = LN(xn + h_last) fp32 ----------------
__global__ __launch_bounds__(256) void ln2_kernel(const u16* __restrict__ xn,
    const float* __restrict__ h_last, const float* __restrict__ gam,
    const float* __restrict__ bet, float* __restrict__ out) {
  int row = blockIdx.x; int tid = threadIdx.x;
  int bi = row >> 9;
  ushort4v xv = *(const ushort4v*)(xn + (size_t)row * D_ + tid * 4);
  float4 hv = *(const float4*)(h_last + (size_t)bi * D_ + tid * 4);
  float s0 = bf2f(xv.x) + hv.x;
  float s1 = bf2f(xv.y) + hv.y;
  float s2 = bf2f(xv.z) + hv.z;
  float s3 = bf2f(xv.w) + hv.w;
  float s = s0 + s1 + s2 + s3;
  float ss = s0*s0 + s1*s1 + s2*s2 + s3*s3;
  #pragma unroll
  for (int o = 32; o > 0; o >>= 1) { s += __shfl_down(s, o); ss += __shfl_down(ss, o); }
  __shared__ float red[8];
  int w = tid >> 6, l = tid & 63;
  if (l == 0) { red[w] = s; red[4 + w] = ss; }
  __syncthreads();
  s  = red[0] + red[1] + red[2] + red[3];
  ss = red[4] + red[5] + red[6] + red[7];
  float mean = s * (1.f / D_);
  float var  = ss * (1.f / D_) - mean * mean;
  float rstd = rsqrtf(var + 1e-3f);
  float4 g = *(const float4*)(gam + tid * 4);
  float4 b = *(const float4*)(bet + tid * 4);
  float4 o4;
  o4.x = (s0 - mean) * rstd * g.x + b.x;
  o4.y = (s1 - mean) * rstd * g.y + b.y;
  o4.z = (s2 - mean) * rstd * g.z + b.z;
  o4.w = (s3 - mean) * rstd * g.w + b.w;
  *(float4*)(out + (size_t)row * D_ + tid * 4) = o4;
}

extern "C" void kernel_launch(void* const* d_in, const int* in_sizes, int n_in,
                              void* d_out, int out_size, void* d_ws, size_t ws_size,
                              hipStream_t stream) {
  const float* x    = (const float*)d_in[0];
  const float* g1   = (const float*)d_in[1];
  const float* b1   = (const float*)d_in[2];
  const float* Wk   = (const float*)d_in[3];
  const float* Wr   = (const float*)d_in[4];
  const float* bias = (const float*)d_in[5];
  const float* g2   = (const float*)d_in[6];
  const float* b2   = (const float*)d_in[7];
  char* ws = (char*)d_ws;
  u16* xn    = (u16*)(ws + OFF_XN);
  u16* KT    = (u16*)(ws + OFF_KT);
  u16* RT    = (u16*)(ws + OFF_RT);
  u16* hbuf  = (u16*)(ws + OFF_HB);
  u32* flg   = (u32*)(ws + OFF_FLG);
  float* hl  = (float*)(ws + OFF_HL);
  float* out = (float*)d_out;

  init_kernel<<<128, 256, 0, stream>>>((u32*)hbuf, flg);
  ln1_kernel<<<B_ * T_, 256, 0, stream>>>(x, g1, b1, xn);
  transpose_bf16<<<dim3(128, 32), dim3(32, 8), 0, stream>>>(Wk, KT);
  transpose_bf16<<<dim3(128, 32), dim3(32, 8), 0, stream>>>(Wr, RT);
  lstm_scan<<<NWG, 512, 0, stream>>>(xn, KT, RT, bias, hbuf, hl, flg);
  ln2_kernel<<<B_ * T_, 256, 0, stream>>>(xn, hl, g2, b2, out);
}

// Round 23
// 1476.563 us; speedup vs baseline: 1.4221x; 1.0914x over previous
//
#include <hip/hip_runtime.h>

typedef unsigned short u16;
typedef unsigned int   u32;
typedef unsigned long long u64;
typedef __attribute__((ext_vector_type(8)))  short  short8v;   // 8 x bf16 (as i16)
typedef __attribute__((ext_vector_type(4)))  float  f32x4;
typedef __attribute__((ext_vector_type(4)))  unsigned short ushort4v;
typedef __attribute__((ext_vector_type(4)))  u32 u32x4;

#define B_   32
#define T_   512
#define D_   1024
#define N4_  4096
#define NWG  256         // scan WGs: 128 unit-groups (8 units) x 2 batch halves (16 rows)

// ---- workspace layout (bytes) ----
#define OFF_XN   0ull                 // xn bf16   [32*512*1024]      33554432
#define OFF_HL   33554432ull          // h_last fp32 [32][1024]         131072
#define OFF_KT   167772160ull         // kernel^T bf16 [4096][1024]    8388608
#define OFF_RT   176160768ull         // recurrent^T bf16 [4096][1024] 8388608
#define OFF_HB   184549376ull         // h double buffer bf16 2*[32][1024] = 131072
#define OFF_FLG  184680448ull         // flags: 512 x 64B-strided u32 (2 gate-wave flags per WG)

__device__ inline u16 f2bf(float f) {
  union { float f; u32 u; } x; x.f = f;
  u32 r = x.u + 0x7FFFu + ((x.u >> 16) & 1u);   // RNE
  return (u16)(r >> 16);
}
__device__ inline float bf2f(u16 h) {
  union { u32 u; float f; } x; x.u = ((u32)h) << 16; return x.f;
}
__device__ inline float sigm(float x) { return 1.f / (1.f + __expf(-x)); }
__device__ inline float tanh_fast(float x) {
  float e = __expf(2.f * x);
  return 1.f - 2.f / (e + 1.f);
}

// ---------------- init: zero h buffers + flags ----------------
__global__ __launch_bounds__(256) void init_kernel(u32* hbuf, u32* flags) {
  int i = blockIdx.x * 256 + threadIdx.x;
  if (i < 32768) hbuf[i] = 0u;       // both parities: 2*32*1024 bf16 = 32768 dwords
  if (i < 512)   flags[i * 16] = 0u;
}

// ---------------- LN1: x fp32 -> xn bf16 ----------------
__global__ __launch_bounds__(256) void ln1_kernel(const float* __restrict__ x,
    const float* __restrict__ gam, const float* __restrict__ bet, u16* __restrict__ xn) {
  int row = blockIdx.x; int tid = threadIdx.x;
  const float* xr = x + (size_t)row * D_;
  float4 v = *(const float4*)(xr + tid * 4);
  float s  = v.x + v.y + v.z + v.w;
  float ss = v.x*v.x + v.y*v.y + v.z*v.z + v.w*v.w;
  #pragma unroll
  for (int o = 32; o > 0; o >>= 1) { s += __shfl_down(s, o); ss += __shfl_down(ss, o); }
  __shared__ float red[8];
  int w = tid >> 6, l = tid & 63;
  if (l == 0) { red[w] = s; red[4 + w] = ss; }
  __syncthreads();
  s  = red[0] + red[1] + red[2] + red[3];
  ss = red[4] + red[5] + red[6] + red[7];
  float mean = s * (1.f / D_);
  float var  = ss * (1.f / D_) - mean * mean;
  float rstd = rsqrtf(var + 1e-3f);
  float4 g = *(const float4*)(gam + tid * 4);
  float4 b = *(const float4*)(bet + tid * 4);
  ushort4v o4;
  o4.x = f2bf((v.x - mean) * rstd * g.x + b.x);
  o4.y = f2bf((v.y - mean) * rstd * g.y + b.y);
  o4.z = f2bf((v.z - mean) * rstd * g.z + b.z);
  o4.w = f2bf((v.w - mean) * rstd * g.w + b.w);
  *(ushort4v*)(xn + (size_t)row * D_ + tid * 4) = o4;
}

// ---------------- transpose [1024][4096] fp32 -> [4096][1024] bf16 ----------------
__global__ __launch_bounds__(256) void transpose_bf16(const float* __restrict__ W, u16* __restrict__ WT) {
  __shared__ float tile[32][33];
  int c0 = blockIdx.x * 32, r0 = blockIdx.y * 32;
  int tx = threadIdx.x, ty = threadIdx.y;
  #pragma unroll
  for (int i = ty; i < 32; i += 8)
    tile[i][tx] = W[(size_t)(r0 + i) * N4_ + c0 + tx];
  __syncthreads();
  #pragma unroll
  for (int i = ty; i < 32; i += 8)
    WT[(size_t)(c0 + i) * D_ + r0 + tx] = f2bf(tile[tx][i]);
}

// ---------------- persistent LSTM scan (R23 = R20 champion, final structure) ----------------
// 256 WGs x 512 thr = 128 unit-groups (8 units, 32 gate-cols) x 2 batch halves
// (16 rows). Fused Zx GEMM at top (no separate GEMM kernel, no Zx HBM round
// trip), centralized wave0 poll + s_barrier release, coalesced LDS h-staging,
// 2-wave gates with per-gate-wave flags (wave-local drain; no post-gate
// __syncthreads). Chain probes R15/R16/R21/R22 all regressed — this structure
// is the sync-latency optimum for the 512-step serial scan (~2.84us/step:
// cross-XCD flag propagation + coherent h exchange + barriers + gates).
__global__ __launch_bounds__(512) __attribute__((amdgpu_waves_per_eu(2, 2)))
void lstm_scan(const u16* __restrict__ xn, const u16* __restrict__ KT,
    const u16* __restrict__ RT, const float* __restrict__ bias,
    u16* hbuf, float* h_last, u32* flags) {
  __shared__ u16   h_lds[16 * D_];           // 32 KB, XOR-swizzled rows (16 batch rows)
  __shared__ float z_lds[8 * 16 * 36];       // 18 KB: [ks][row16][32 cols + 4 pad]
  int tid = threadIdx.x;
  int wg = blockIdx.x;
  int ug = wg >> 1, bh = wg & 1;             // unit-group, batch half
  int w = tid >> 6, l = tid & 63;
  int ks = w;                                // K-split: ks*128..+128
  int fr = l & 15, hi = l >> 4;              // fragment row 0..15, k-quarter 0..3

  // B fragments: col c = ch*16+fr -> unit ug*8+(c>>2), gate c&3.
  short8v bR[4][2], bK[4][2];
  #pragma unroll
  for (int ch = 0; ch < 2; ++ch) {
    int c = ch * 16 + fr;
    size_t rowoff = (size_t)((c & 3) * 1024 + ug * 8 + (c >> 2)) * D_
                  + ks * 128 + hi * 8;
    const u16* Rp = RT + rowoff;
    const u16* Kp = KT + rowoff;
    #pragma unroll
    for (int kt = 0; kt < 4; ++kt) {
      bR[kt][ch] = *(const short8v*)(Rp + kt * 32);
      bK[kt][ch] = *(const short8v*)(Kp + kt * 32);
    }
  }
  #pragma unroll
  for (int kt = 0; kt < 4; ++kt) {
    asm volatile("" : "+v"(bR[kt][0]));
    asm volatile("" : "+v"(bR[kt][1]));
    asm volatile("" : "+v"(bK[kt][0]));
    asm volatile("" : "+v"(bK[kt][1]));
  }

  // xn A-operand pointer: row b = bh*16+fr, time t
  const u16* xnp = xn + (size_t)(bh * 16 + fr) * 512 * D_ + ks * 128 + hi * 8;
  // h A-fragment addressing (staged LDS, swizzled)
  int abase = fr * 2048 + ks * 256 + hi * 16;
  int asw = (fr & 7) << 4;
  // gate cell (tid < 128): local batch row grow (0..15), unit gu (0..7)
  int grow = tid >> 3, gu = tid & 7;
  int hoff = (bh * 16 + grow) * D_ + ug * 8 + gu;
  float c = 0.f;
  float bi0 = 0.f, bf0 = 0.f, bg0 = 0.f, bo0 = 0.f;
  if (tid < 128) {
    int u = ug * 8 + gu;
    bi0 = bias[u]; bf0 = bias[1024 + u]; bg0 = bias[2048 + u]; bo0 = bias[3072 + u];
  }
  // wave0 poll: 128 same-bh WGs x 2 gate-flags = 4 per lane
  // flag index for (wg', gw) = (wg'*2+gw); wg' = ug'*2+bh
  const u32* fpA0 = flags + (size_t)((2 * l + bh) * 2 + 0) * 16;
  const u32* fpA1 = flags + (size_t)((2 * l + bh) * 2 + 1) * 16;
  const u32* fpB0 = flags + (size_t)((2 * (64 + l) + bh) * 2 + 0) * 16;
  const u32* fpB1 = flags + (size_t)((2 * (64 + l) + bh) * 2 + 1) * 16;

  #pragma unroll 1
  for (int t = 0; t < T_; ++t) {
    // (1) fused Zx part: 4 direct xn loads (cached) + 8 MFMAs — no h dependency
    f32x4 acc0, acc1;
    #pragma unroll
    for (int i = 0; i < 4; ++i) { acc0[i] = 0.f; acc1[i] = 0.f; }
    {
      short8v ax[4];
      #pragma unroll
      for (int kt = 0; kt < 4; ++kt) ax[kt] = *(const short8v*)(xnp + kt * 32);
      #pragma unroll
      for (int kt = 0; kt < 4; ++kt) {
        acc0 = __builtin_amdgcn_mfma_f32_16x16x32_bf16(ax[kt], bK[kt][0], acc0, 0, 0, 0);
        acc1 = __builtin_amdgcn_mfma_f32_16x16x32_bf16(ax[kt], bK[kt][1], acc1, 0, 0, 0);
      }
    }
    __builtin_amdgcn_sched_barrier(0);

    // (2) wave0 polls same-bh flags (both gate waves); s_barrier releases the rest
    if (w == 0) {
      u32 t32 = (u32)t;
      while (true) {
        u32 a0 = __hip_atomic_load(fpA0, __ATOMIC_RELAXED, __HIP_MEMORY_SCOPE_AGENT);
        u32 a1 = __hip_atomic_load(fpA1, __ATOMIC_RELAXED, __HIP_MEMORY_SCOPE_AGENT);
        u32 b0 = __hip_atomic_load(fpB0, __ATOMIC_RELAXED, __HIP_MEMORY_SCOPE_AGENT);
        u32 b1 = __hip_atomic_load(fpB1, __ATOMIC_RELAXED, __HIP_MEMORY_SCOPE_AGENT);
        if (__all((int)(a0 >= t32 && a1 >= t32 && b0 >= t32 && b1 >= t32))) break;
      }
    }
    __builtin_amdgcn_s_barrier();
    __builtin_amdgcn_sched_barrier(0);

    // (3) bulk-load h for our 16 batch rows: 4 x 16B per thread (32KB, coalesced)
    const char* hbp = (const char*)hbuf + (size_t)(t & 1) * 65536 + (size_t)bh * 32768;
    u32x4 hv[4];
    #pragma unroll
    for (int j = 0; j < 4; ++j) {
      const char* p = hbp + j * 8192 + tid * 16;
      asm volatile("global_load_dwordx4 %0, %1, off sc0 sc1"
                   : "=&v"(hv[j]) : "v"(p) : "memory");
    }
    asm volatile("s_waitcnt vmcnt(0)" ::: "memory");
    __builtin_amdgcn_sched_barrier(0);
    #pragma unroll
    for (int j = 0; j < 4; ++j) {
      int byte = j * 8192 + tid * 16;
      int row = byte >> 11;
      *(u32x4*)((char*)h_lds + (byte ^ ((row & 7) << 4))) = hv[j];
    }
    __syncthreads();

    // (4) h-part: 4 K-steps x (1 ds_read_b128 + 2 mfma 16x16x32) onto Zx accs
    #pragma unroll
    for (int kt = 0; kt < 4; ++kt) {
      short8v a = *(const short8v*)((const char*)h_lds + ((abase + kt * 64) ^ asw));
      acc0 = __builtin_amdgcn_mfma_f32_16x16x32_bf16(a, bR[kt][0], acc0, 0, 0, 0);
      acc1 = __builtin_amdgcn_mfma_f32_16x16x32_bf16(a, bR[kt][1], acc1, 0, 0, 0);
    }
    // write K-partials: 16x16 D layout row=hi*4+j, col=fr
    #pragma unroll
    for (int j = 0; j < 4; ++j) {
      int rowD = hi * 4 + j;
      z_lds[(ks * 16 + rowD) * 36 + fr]      = acc0[j];
      z_lds[(ks * 16 + rowD) * 36 + 16 + fr] = acc1[j];
    }
    __syncthreads();   // z visible to gate waves; ALSO proves all h(t) reads done

    // (5) gates: waves 0-1 (128 thr, one cell each); waves 2-7 go straight to t+1
    if (tid < 128) {
      float z0 = bi0, z1 = bf0, z2 = bg0, z3 = bo0;
      #pragma unroll
      for (int kss = 0; kss < 8; ++kss) {
        f32x4 zr = *(const f32x4*)&z_lds[(kss * 16 + grow) * 36 + gu * 4];
        z0 += zr[0]; z1 += zr[1]; z2 += zr[2]; z3 += zr[3];
      }
      float cn = sigm(z1) * c + sigm(z0) * tanh_fast(z2);
      float hn = sigm(z3) * tanh_fast(cn);
      c = cn;

      // publish h (pair adjacent units -> u32 agent-scope store)
      u32 hw = (u32)f2bf(hn);
      u32 nb = __shfl_down(hw, 1);
      if (!(gu & 1)) {
        u32* dst = (u32*)(hbuf + (size_t)((t + 1) & 1) * (B_ * D_) + hoff);
        __hip_atomic_store(dst, hw | (nb << 16), __ATOMIC_RELAXED, __HIP_MEMORY_SCOPE_AGENT);
      }
      if (t == T_ - 1) h_last[hoff] = hn;
      // wave-local drain, then set THIS gate wave's flag (no cross-wave barrier)
      asm volatile("s_waitcnt vmcnt(0)" ::: "memory");
      if (l == 0)
        __hip_atomic_store(flags + (size_t)(wg * 2 + w) * 16, (u32)(t + 1),
                           __ATOMIC_RELAXED, __HIP_MEMORY_SCOPE_AGENT);
    }
    xnp += D_;
  }
}

// ---------------- LN2: out = LN(xn + h_last) fp32 ----------------
__global__ __launch_bounds__(256) void ln2_kernel(const u16* __restrict__ xn,
    const float* __restrict__ h_last, const float* __restrict__ gam,
    const float* __restrict__ bet, float* __restrict__ out) {
  int row = blockIdx.x; int tid = threadIdx.x;
  int bi = row >> 9;
  ushort4v xv = *(const ushort4v*)(xn + (size_t)row * D_ + tid * 4);
  float4 hv = *(const float4*)(h_last + (size_t)bi * D_ + tid * 4);
  float s0 = bf2f(xv.x) + hv.x;
  float s1 = bf2f(xv.y) + hv.y;
  float s2 = bf2f(xv.z) + hv.z;
  float s3 = bf2f(xv.w) + hv.w;
  float s = s0 + s1 + s2 + s3;
  float ss = s0*s0 + s1*s1 + s2*s2 + s3*s3;
  #pragma unroll
  for (int o = 32; o > 0; o >>= 1) { s += __shfl_down(s, o); ss += __shfl_down(ss, o); }
  __shared__ float red[8];
  int w = tid >> 6, l = tid & 63;
  if (l == 0) { red[w] = s; red[4 + w] = ss; }
  __syncthreads();
  s  = red[0] + red[1] + red[2] + red[3];
  ss = red[4] + red[5] + red[6] + red[7];
  float mean = s * (1.f / D_);
  float var  = ss * (1.f / D_) - mean * mean;
  float rstd = rsqrtf(var + 1e-3f);
  float4 g = *(const float4*)(gam + tid * 4);
  float4 b = *(const float4*)(bet + tid * 4);
  float4 o4;
  o4.x = (s0 - mean) * rstd * g.x + b.x;
  o4.y = (s1 - mean) * rstd * g.y + b.y;
  o4.z = (s2 - mean) * rstd * g.z + b.z;
  o4.w = (s3 - mean) * rstd * g.w + b.w;
  *(float4*)(out + (size_t)row * D_ + tid * 4) = o4;
}

extern "C" void kernel_launch(void* const* d_in, const int* in_sizes, int n_in,
                              void* d_out, int out_size, void* d_ws, size_t ws_size,
                              hipStream_t stream) {
  const float* x    = (const float*)d_in[0];
  const float* g1   = (const float*)d_in[1];
  const float* b1   = (const float*)d_in[2];
  const float* Wk   = (const float*)d_in[3];
  const float* Wr   = (const float*)d_in[4];
  const float* bias = (const float*)d_in[5];
  const float* g2   = (const float*)d_in[6];
  const float* b2   = (const float*)d_in[7];
  char* ws = (char*)d_ws;
  u16* xn    = (u16*)(ws + OFF_XN);
  u16* KT    = (u16*)(ws + OFF_KT);
  u16* RT    = (u16*)(ws + OFF_RT);
  u16* hbuf  = (u16*)(ws + OFF_HB);
  u32* flg   = (u32*)(ws + OFF_FLG);
  float* hl  = (float*)(ws + OFF_HL);
  float* out = (float*)d_out;

  init_kernel<<<128, 256, 0, stream>>>((u32*)hbuf, flg);
  ln1_kernel<<<B_ * T_, 256, 0, stream>>>(x, g1, b1, xn);
  transpose_bf16<<<dim3(128, 32), dim3(32, 8), 0, stream>>>(Wk, KT);
  transpose_bf16<<<dim3(128, 32), dim3(32, 8), 0, stream>>>(Wr, RT);
  lstm_scan<<<NWG, 512, 0, stream>>>(xn, KT, RT, bias, hbuf, hl, flg);
  ln2_kernel<<<B_ * T_, 256, 0, stream>>>(xn, hl, g2, b2, out);
}